// Round 15
// baseline (489.198 us; speedup 1.0000x reference)
//
#include <hip/hip_runtime.h>

typedef unsigned short u16;
typedef unsigned int u32;
typedef __attribute__((ext_vector_type(8))) short short8;
typedef __attribute__((ext_vector_type(4))) float f32x4;

// ---------- bf16 helpers ----------
__device__ inline u16 f2b(float f) {  // RNE
  u32 u = __builtin_bit_cast(u32, f);
  u += 0x7fff + ((u >> 16) & 1);
  return (u16)(u >> 16);
}
__device__ inline float b2f(u16 u) {
  return __builtin_bit_cast(float, (u32)u << 16);
}
// round-to-nearest (ties away) pack — cheaper than RNE, used for P only
__device__ inline u32 pack_bf16_rn(float a, float b) {
  const u32 ua = __builtin_bit_cast(u32, a) + 0x8000u;
  const u32 ub = __builtin_bit_cast(u32, b) + 0x8000u;
  return (ua >> 16) | (ub & 0xffff0000u);
}
__device__ inline void c_store(float* p, float v) { *p = v; }
__device__ inline void c_store(u16* p, float v) { *p = f2b(v); }

__device__ inline float fexp2(float x) {
#if __has_builtin(__builtin_amdgcn_exp2f)
  return __builtin_amdgcn_exp2f(x);
#else
  return exp2f(x);
#endif
}

// ---------- async global->LDS, 16B per lane ----------
typedef const __attribute__((address_space(1))) u32 gu32;
typedef __attribute__((address_space(3))) u32 lu32;
__device__ inline void async16(const u16* g, u16* l) {
  __builtin_amdgcn_global_load_lds((gu32*)g, (lu32*)l, 16, 0, 0);
}

// Q scale folded into rmsnorm producer: 1/sqrt(128) * log2(e)
#define QS (0.08838834764831843f * 1.4426950408889634f)

// =====================================================================
// (32*MI)x128x(K,BK=32) bf16 GEMM. r14 structure (verified r8/r12-r14):
// single-barrier LDS double-buffer + XCD-locality remap.
// Used for the output projection only.
// =====================================================================
template <int MI, typename TC>
__global__ __launch_bounds__(256) void gemm128_kernel(
    const u16* __restrict__ A, long lda,
    const u16* __restrict__ Bt, long ldb,
    TC* __restrict__ C0, TC* __restrict__ C1, TC* __restrict__ C2, long ldc,
    const float* b0, const float* b1, const float* b2,
    int K) {
  __shared__ __align__(16) u16 As[2][32 * MI * 32];
  __shared__ __align__(16) u16 Bs[2][128 * 32];

  const int tid = threadIdx.x;
  const int lane = tid & 63;
  const int w = tid >> 6;
  const int r = lane & 15;
  const int quad = lane >> 4;

  // ---- XCD-locality remap (bijective when ny % 8 == 0) ----
  int bx = blockIdx.x, by = blockIdx.y;
  {
    const int ny = gridDim.y;
    if ((ny & 7) == 0) {
      const int lin = by * gridDim.x + bx;
      const int xcd = lin & 7;
      const int k = lin >> 3;
      const int rpx = ny >> 3;                 // A-row panels per XCD
      by = xcd * rpx + (k % rpx);
      bx = k / rpx;
    }
  }
  const int m0 = by * (32 * MI);
  const int nb = bx * 128;
  const int seg = nb / 1536;
  const int nc = nb - seg * 1536;
  TC* C = seg == 0 ? C0 : (seg == 1 ? C1 : C2);
  const float* bias = seg == 0 ? b0 : (seg == 1 ? b1 : b2);

  const int srow = lane >> 2;
  const int sx = ((lane & 3) ^ (srow & 3)) * 8;
  const u16* Ag = A + (size_t)(m0 + w * 8 * MI + srow) * lda + sx;
  const u16* Bg = Bt + (size_t)(nb + w * 32 + srow) * ldb + sx;

  const int wm = (w >> 1) * (16 * MI);
  const int wn = (w & 1) * 64;

  f32x4 acc[MI][4];
#pragma unroll
  for (int i = 0; i < MI; ++i)
#pragma unroll
    for (int j = 0; j < 4; ++j) acc[i][j] = (f32x4){0.f, 0.f, 0.f, 0.f};

  const int fco = (quad ^ (r & 3)) * 8;

  const int nt = K >> 5;

  // prologue: stage tile 0 into buffer 0
#pragma unroll
  for (int j = 0; j < MI / 2; ++j)
    async16(Ag + (size_t)(16 * j) * lda, &As[0][(w * 8 * MI + 16 * j) * 32]);
  async16(Bg, &Bs[0][(w * 32) * 32]);
  async16(Bg + 16 * ldb, &Bs[0][(w * 32 + 16) * 32]);

  for (int t = 0; t < nt; ++t) {
    const int buf = t & 1;
    __syncthreads();  // stage(t) complete; buf^1 reads (iter t-1) done
    if (t + 1 < nt) {
      const int kk = 32 * (t + 1);
#pragma unroll
      for (int j = 0; j < MI / 2; ++j)
        async16(Ag + kk + (size_t)(16 * j) * lda, &As[buf ^ 1][(w * 8 * MI + 16 * j) * 32]);
      async16(Bg + kk, &Bs[buf ^ 1][(w * 32) * 32]);
      async16(Bg + kk + 16 * ldb, &Bs[buf ^ 1][(w * 32 + 16) * 32]);
    }

    short8 af[MI], bf[4];
#pragma unroll
    for (int mi = 0; mi < MI; ++mi)
      af[mi] = *reinterpret_cast<const short8*>(&As[buf][(wm + 16 * mi + r) * 32 + fco]);
#pragma unroll
    for (int ni = 0; ni < 4; ++ni)
      bf[ni] = *reinterpret_cast<const short8*>(&Bs[buf][(wn + 16 * ni + r) * 32 + fco]);
#pragma unroll
    for (int mi = 0; mi < MI; ++mi)
#pragma unroll
      for (int ni = 0; ni < 4; ++ni)
        acc[mi][ni] = __builtin_amdgcn_mfma_f32_16x16x32_bf16(af[mi], bf[ni], acc[mi][ni], 0, 0, 0);
  }

#pragma unroll
  for (int mi = 0; mi < MI; ++mi)
#pragma unroll
    for (int ni = 0; ni < 4; ++ni)
#pragma unroll
      for (int rr = 0; rr < 4; ++rr) {
        const int row = m0 + wm + 16 * mi + 4 * quad + rr;
        const int col = nc + wn + 16 * ni + r;
        c_store(&C[(size_t)row * ldc + col], acc[mi][ni][rr] + bias[col]);
      }
}

// =====================================================================
// Merged QKV + KrVr GEMM. Body = gemm128 MI=4 verbatim (verified
// r13/r14). r21 change: 2D rectangular XCD chunking in the decode.
//  r14 counter evidence: FETCH 160.9 MB for ~44 MB unique operands —
//  the 1D swz gave each XCD ~4.7 A-panels x ALL 36 B-panels (full-B
//  stream per XCD). 2D rectangles cut per-XCD operand footprint:
//   QKV: 32x36 panel grid -> 8 rects of 16by x 9bx (9.8 MB/XCD vs 16.6)
//        XCD x: xr=x>>2 (2 row-groups), xc=x&3 (4 col-groups).
//   KrVr: 8x24 grid -> 8 rects of 4by x 6bx (4 MB/XCD vs 9.8)
//        XCD x: xr2=x&1, xc2=x>>1.
//  Walk bx'-outer so each B panel is reused by 16 (resp 4) adjacent
//  blocks while the A rectangle stays L2-warm. Bijective (checked).
//  XCD assignment model: hw round-robins blockIdx.x % 8 (r13-validated
//  swizzle family).
// =====================================================================
__global__ __launch_bounds__(256) void gemm_qkvr_kernel(
    const u16* __restrict__ A1, const u16* __restrict__ B1,
    u16* __restrict__ Cq, u16* __restrict__ Ck, u16* __restrict__ Cv,
    const float* bq, const float* bk, const float* bv,
    const u16* __restrict__ A2, const u16* __restrict__ B2,
    u16* __restrict__ Ckr, u16* __restrict__ Cvr,
    const float* bkr, const float* bvr) {
  constexpr int MI = 4;
  __shared__ __align__(16) u16 As[2][32 * MI * 32];
  __shared__ __align__(16) u16 Bs[2][128 * 32];

  const int tid = threadIdx.x;
  const int lane = tid & 63;
  const int w = tid >> 6;
  const int r = lane & 15;
  const int quad = lane >> 4;

  // ---- decode: 2D-rect XCD chunking, then GEMM select ----
  const int x = blockIdx.x & 7;               // XCD (hw round-robin)
  const int k = blockIdx.x >> 3;              // 0..167 within XCD
  const u16 *A, *Bt;
  u16* C;
  const float* bias;
  int m0, nb, nc;
  if (k < 144) {                              // QKV: rect 16by x 9bx
    const int by = (x >> 2) * 16 + (k & 15);  // k%16 fast: B panel reused
    const int bx = (x & 3) * 9 + (k >> 4);
    m0 = by * 128;
    nb = bx * 128;
    const int seg = nb / 1536;
    nc = nb - seg * 1536;
    A = A1; Bt = B1;
    C = seg == 0 ? Cq : (seg == 1 ? Ck : Cv);
    bias = seg == 0 ? bq : (seg == 1 ? bk : bv);
  } else {                                    // KrVr: rect 4by x 6bx
    const int k2 = k - 144;                   // 0..23
    const int by = (x & 1) * 4 + (k2 & 3);
    const int bx = (x >> 1) * 6 + (k2 >> 2);
    m0 = by * 128;                            // < 1024
    nb = bx * 128;                            // < 3072
    const int seg = (nb >= 1536) ? 1 : 0;
    nc = nb - seg * 1536;
    A = A2; Bt = B2;
    C = seg == 0 ? Ckr : Cvr;
    bias = seg == 0 ? bkr : bvr;
  }

  const int srow = lane >> 2;
  const int sx = ((lane & 3) ^ (srow & 3)) * 8;
  const u16* Ag = A + (size_t)(m0 + w * 8 * MI + srow) * 1536 + sx;
  const u16* Bg = Bt + (size_t)(nb + w * 32 + srow) * 1536 + sx;

  const int wm = (w >> 1) * (16 * MI);
  const int wn = (w & 1) * 64;

  f32x4 acc[MI][4];
#pragma unroll
  for (int i = 0; i < MI; ++i)
#pragma unroll
    for (int j = 0; j < 4; ++j) acc[i][j] = (f32x4){0.f, 0.f, 0.f, 0.f};

  const int fco = (quad ^ (r & 3)) * 8;

  const int nt = 1536 >> 5;  // 48

  // prologue: stage tile 0 into buffer 0
#pragma unroll
  for (int j = 0; j < MI / 2; ++j)
    async16(Ag + (size_t)(16 * j) * 1536, &As[0][(w * 8 * MI + 16 * j) * 32]);
  async16(Bg, &Bs[0][(w * 32) * 32]);
  async16(Bg + 16 * 1536, &Bs[0][(w * 32 + 16) * 32]);

  for (int t = 0; t < nt; ++t) {
    const int buf = t & 1;
    __syncthreads();  // stage(t) complete; buf^1 reads (iter t-1) done
    if (t + 1 < nt) {
      const int kk = 32 * (t + 1);
#pragma unroll
      for (int j = 0; j < MI / 2; ++j)
        async16(Ag + kk + (size_t)(16 * j) * 1536, &As[buf ^ 1][(w * 8 * MI + 16 * j) * 32]);
      async16(Bg + kk, &Bs[buf ^ 1][(w * 32) * 32]);
      async16(Bg + kk + 16 * 1536, &Bs[buf ^ 1][(w * 32 + 16) * 32]);
    }

    short8 af[MI], bf[4];
#pragma unroll
    for (int mi = 0; mi < MI; ++mi)
      af[mi] = *reinterpret_cast<const short8*>(&As[buf][(wm + 16 * mi + r) * 32 + fco]);
#pragma unroll
    for (int ni = 0; ni < 4; ++ni)
      bf[ni] = *reinterpret_cast<const short8*>(&Bs[buf][(wn + 16 * ni + r) * 32 + fco]);
#pragma unroll
    for (int mi = 0; mi < MI; ++mi)
#pragma unroll
      for (int ni = 0; ni < 4; ++ni)
        acc[mi][ni] = __builtin_amdgcn_mfma_f32_16x16x32_bf16(af[mi], bf[ni], acc[mi][ni], 0, 0, 0);
  }

#pragma unroll
  for (int mi = 0; mi < MI; ++mi)
#pragma unroll
    for (int ni = 0; ni < 4; ++ni)
#pragma unroll
      for (int rr = 0; rr < 4; ++rr) {
        const int row = m0 + wm + 16 * mi + 4 * quad + rr;
        const int col = nc + wn + 16 * ni + r;
        c_store(&C[(size_t)row * 1536 + col], acc[mi][ni][rr] + bias[col]);
      }
}

// =====================================================================
// Fused prep (verified r14): conv2 (z=0) + transconv6 (z=1).
// =====================================================================
__global__ __launch_bounds__(256) void prep_kernel(
    const float* __restrict__ hs, u16* __restrict__ yhs, int n8a,
    const float* __restrict__ rhs, u16* __restrict__ yrhs, int n8b,
    const float* W0, const float* W1, const float* W2,
    const float* W3, const float* W4, const float* W5,
    u16* T0, u16* T1, u16* T2, u16* T3, u16* T4, u16* T5) {
  const int tid = threadIdx.x;
  if (blockIdx.z == 0) {
    // ---- conv2 body (verified r0-r14) ----
    int i = blockIdx.x * 256 + tid;
    const float* x;
    u16* y;
    if (i < n8a) {
      x = hs; y = yhs;
    } else {
      i -= n8a;
      if (i >= n8b) return;
      x = rhs; y = yrhs;
    }
    const float4 v0 = reinterpret_cast<const float4*>(x)[2 * i];
    const float4 v1 = reinterpret_cast<const float4*>(x)[2 * i + 1];
    uint4 rv;
    rv.x = (u32)f2b(v0.x) | ((u32)f2b(v0.y) << 16);
    rv.y = (u32)f2b(v0.z) | ((u32)f2b(v0.w) << 16);
    rv.z = (u32)f2b(v1.x) | ((u32)f2b(v1.y) << 16);
    rv.w = (u32)f2b(v1.z) | ((u32)f2b(v1.w) << 16);
    reinterpret_cast<uint4*>(y)[i] = rv;
    return;
  }
  // ---- transconv6 body (verified r0-r14), lin-decoded ----
  const int lin = blockIdx.x;
  if (lin >= 3456) return;
  const int bx = lin % 24;
  const int by = (lin / 24) % 24;
  const int z = lin / 576;
  const float* W = z == 0 ? W0 : z == 1 ? W1 : z == 2 ? W2 : z == 3 ? W3 : z == 4 ? W4 : W5;
  u16* Wt = z == 0 ? T0 : z == 1 ? T1 : z == 2 ? T2 : z == 3 ? T3 : z == 4 ? T4 : T5;

  __shared__ __align__(16) u16 Ls[64 * 72];
  const int k0 = by * 64;
  const int n0 = bx * 64;
#pragma unroll
  for (int i = 0; i < 4; ++i) {
    const int c = tid + 256 * i;
    const int row = c >> 4;
    const int c4 = (c & 15) * 4;
    const float4 v = *reinterpret_cast<const float4*>(&W[(size_t)(k0 + row) * 1536 + n0 + c4]);
    Ls[(c4 + 0) * 72 + row] = f2b(v.x);
    Ls[(c4 + 1) * 72 + row] = f2b(v.y);
    Ls[(c4 + 2) * 72 + row] = f2b(v.z);
    Ls[(c4 + 3) * 72 + row] = f2b(v.w);
  }
  __syncthreads();
#pragma unroll
  for (int i = 0; i < 2; ++i) {
    const int c = tid + 256 * i;
    const int n = c >> 3;
    const int kc = (c & 7) * 8;
    u16 tmp[8];
#pragma unroll
    for (int j = 0; j < 8; ++j) tmp[j] = Ls[n * 72 + kc + j];
    *reinterpret_cast<uint4*>(&Wt[(size_t)(n0 + n) * 1536 + k0 + kc]) =
        *reinterpret_cast<const uint4*>(tmp);
  }
}

// =====================================================================
// Fused norm (verified r14): rmsnorm3 (lin<12288) + vtrans2 (rest).
// =====================================================================
__global__ __launch_bounds__(256) void normtrans_kernel(
    const u16* xq, const u16* xk, const u16* xkr,
    const float* gq, const float* gk,
    const float* rc, const float* rs,
    u16* oq_plain, u16* oq_rope, u16* ok_rope, u16* okr_plain,
    const u16* __restrict__ V0, u16* __restrict__ Vt0,
    const u16* __restrict__ V1, u16* __restrict__ Vt1) {
  const int tid = threadIdx.x;
  const int lin = blockIdx.x;
  __shared__ __align__(16) u16 LsV[64 * 136];  // vtrans scratch (max LDS)

  if (lin < 12288) {
    // ---- rmsnorm3 body (verified r4-r14) ----
    __shared__ float red[4];
    const int z = lin >> 12;
    const int row = lin & 4095;
    if (z == 2 && row >= 1024) return;
    const u16* x; const float* g; u16* po; u16* pr; float sc;
    if (z == 0)      { x = xq;  g = gq; po = oq_plain; pr = oq_rope; sc = QS;  }
    else if (z == 1) { x = xk;  g = gk; po = nullptr;  pr = ok_rope; sc = 1.f; }
    else             { x = xkr; g = gk; po = okr_plain; pr = nullptr; sc = 1.f; }

    const u32* xr = reinterpret_cast<const u32*>(x + (size_t)row * 1536);
    float xe[3], xo[3];
    float ss = 0.f;
#pragma unroll
    for (int j = 0; j < 3; ++j) {
      const u32 u = xr[tid + 256 * j];
      const float e = b2f((u16)(u & 0xffff));
      const float o = b2f((u16)(u >> 16));
      xe[j] = e; xo[j] = o;
      ss += e * e + o * o;
    }
#pragma unroll
    for (int off = 32; off; off >>= 1) ss += __shfl_xor(ss, off, 64);
    if ((tid & 63) == 0) red[tid >> 6] = ss;
    __syncthreads();
    const float total = red[0] + red[1] + red[2] + red[3];
    const float rinv = rsqrtf(total * (1.0f / 1536.0f) + 1e-6f) * sc;
    u32* po32 = po ? reinterpret_cast<u32*>(po + (size_t)row * 1536) : nullptr;
    u32* pr32 = pr ? reinterpret_cast<u32*>(pr + (size_t)row * 1536) : nullptr;
#pragma unroll
    for (int j = 0; j < 3; ++j) {
      const int p = tid + 256 * j;
      const float2 gg = reinterpret_cast<const float2*>(g)[p];
      const float e = xe[j] * rinv * gg.x;
      const float o = xo[j] * rinv * gg.y;
      if (po32) po32[p] = (u32)f2b(e) | ((u32)f2b(o) << 16);
      if (pr32) {
        const int i = p & 63;
        const float c = rc[row * 64 + i];
        const float s = rs[row * 64 + i];
        const float re = e * c - o * s;
        const float im = e * s + o * c;
        pr32[p] = (u32)f2b(re) | ((u32)f2b(im) << 16);
      }
    }
    return;
  }

  // ---- vtrans2 body (verified r4-r14), lin-decoded ----
  const int s = lin - 12288;         // 0..1535
  const int xb = s & 63;
  const int h = (s >> 6) % 12;
  const int zz = s / 768;
  const int kvLen = zz == 0 ? 4096 : 1024;
  const int kv0 = xb * 64;
  if (kv0 >= kvLen) return;
  const u16* V = zz == 0 ? V0 : V1;
  u16* Vt = zz == 0 ? Vt0 : Vt1;
#pragma unroll
  for (int i = 0; i < 4; ++i) {
    const int c = tid + 256 * i;
    const int row = c >> 4, c8 = c & 15;
    *reinterpret_cast<uint4*>(&LsV[row * 136 + 8 * c8]) =
        *reinterpret_cast<const uint4*>(V + (size_t)(kv0 + row) * 1536 + h * 128 + 8 * c8);
  }
  __syncthreads();
#pragma unroll
  for (int i = 0; i < 4; ++i) {
    const int c = tid + 256 * i;
    const int d = c >> 3, kc = c & 7;
    u16 tmp[8];
#pragma unroll
    for (int j = 0; j < 8; ++j) tmp[j] = LsV[(8 * kc + j) * 136 + d];
    *reinterpret_cast<uint4*>(Vt + ((size_t)h * 128 + d) * kvLen + kv0 + 8 * kc) =
        *reinterpret_cast<const uint4*>(tmp);
  }
}

// =====================================================================
// Flash attention (verified r14, 204 µs): merged cross+main, defer-max,
// s_setprio. Inner loop frozen. Byte-identical to r14 (control).
// =====================================================================
__global__ __launch_bounds__(256, 3) void flash_kernel(
    const u16* __restrict__ Qc, const u16* __restrict__ Kc,
    const u16* __restrict__ Vc, int kvLenC,
    const u16* __restrict__ Qm, const u16* __restrict__ Km,
    const u16* __restrict__ Vm, int kvLenM,
    u16* __restrict__ Ob) {
  __shared__ __align__(16) u16 Ks[64 * 128];
  __shared__ __align__(16) u16 Vs[128 * 64];
  __shared__ __align__(16) u16 Pb[4][16 * 40];
  __shared__ __align__(16) float ab[4][16];

  const int tid = threadIdx.x;
  const int lane = tid & 63;
  const int w = tid >> 6;
  const int r = lane & 15;
  const int quad = lane >> 4;
  const int h = blockIdx.y;
  const int q0 = blockIdx.x * 64;
  const int qrow = q0 + 16 * w + r;
  const int sw = r & 7;

  auto run_pass = [&](const u16* __restrict__ Q, const u16* __restrict__ K,
                      const u16* __restrict__ Vt, int kvLen, f32x4* Oc) {
    // Q fragments (B-operand of S^T): lane holds Q[qrow][32ks+8quad+j]
    short8 qf[4];
    {
      const u16* qbase = Q + (size_t)qrow * 1536 + h * 128 + 8 * quad;
#pragma unroll
      for (int ks = 0; ks < 4; ++ks)
        qf[ks] = *reinterpret_cast<const short8*>(qbase + 32 * ks);
    }

    // staging: uniform bases + 32-bit per-lane element offsets (r0 layout)
    const u16* Kb = K + h * 128;
    const u16* Vb = Vt + (size_t)h * 128 * kvLen;
    u32 koff[4], voff[4];
    int klo[4], vlo[4];
    {
      const int p16 = lane & 15, rin = lane >> 4;
      const int p8 = lane & 7, din = lane >> 3;
#pragma unroll
      for (int j = 0; j < 4; ++j) {
        const int row = 16 * w + 4 * j + rin;
        koff[j] = (u32)row * 1536u + 8u * (u32)(p16 ^ (row & 15));
        klo[j] = (16 * w + 4 * j) * 128;
        const int d = 32 * w + 8 * j + din;
        voff[j] = (u32)d * (u32)kvLen + 8u * (u32)(p8 ^ (d & 7));
        vlo[j] = (32 * w + 8 * j) * 64;
      }
    }

#pragma unroll
    for (int dt = 0; dt < 8; ++dt) Oc[dt] = (f32x4){0.f, 0.f, 0.f, 0.f};
    float m_i = -1e30f, l_i = 0.f;

    const int nt = kvLen >> 6;
    for (int t = 0; t < nt; ++t) {
      __syncthreads();  // prior tile reads done
      {
        const size_t ko = (size_t)t * (64 * 1536);
        const size_t vo = (size_t)t * 64;
#pragma unroll
        for (int j = 0; j < 4; ++j) async16(Kb + ko + koff[j], &Ks[klo[j]]);
#pragma unroll
        for (int j = 0; j < 4; ++j) async16(Vb + vo + voff[j], &Vs[vlo[j]]);
      }
      __syncthreads();  // DMA complete

      // S^T = K * Q^T (log2-domain; Q pre-scaled)
      f32x4 St[4];
#pragma unroll
      for (int mt = 0; mt < 4; ++mt) St[mt] = (f32x4){0.f, 0.f, 0.f, 0.f};
      __builtin_amdgcn_s_setprio(1);
#pragma unroll
      for (int mt = 0; mt < 4; ++mt) {
        const u16* kp = &Ks[(16 * mt + r) * 128];
#pragma unroll
        for (int ks = 0; ks < 4; ++ks) {
          const short8 af = *reinterpret_cast<const short8*>(kp + 8 * ((quad + 4 * ks) ^ r));
          St[mt] = __builtin_amdgcn_mfma_f32_16x16x32_bf16(af, qf[ks], St[mt], 0, 0, 0);
        }
      }
      __builtin_amdgcn_s_setprio(0);

      // online softmax (base 2); lane owns q-row r; defer-max (r13 form)
      float mloc = -1e30f;
#pragma unroll
      for (int mt = 0; mt < 4; ++mt)
#pragma unroll
        for (int rr = 0; rr < 4; ++rr) mloc = fmaxf(mloc, St[mt][rr]);
      mloc = fmaxf(mloc, __shfl_xor(mloc, 16, 64));
      mloc = fmaxf(mloc, __shfl_xor(mloc, 32, 64));

      float alpha = 1.0f;
      if (__any(mloc > m_i + 11.5f)) {  // defer-max: rescale only on big growth
        const float mn = fmaxf(m_i, mloc);
        alpha = fexp2(m_i - mn);
        m_i = mn;
        if (quad == 0) ab[w][r] = alpha;
        const float4 a4 = *reinterpret_cast<const float4*>(&ab[w][4 * quad]);
#pragma unroll
        for (int dt = 0; dt < 8; ++dt) {
          Oc[dt][0] *= a4.x; Oc[dt][1] *= a4.y; Oc[dt][2] *= a4.z; Oc[dt][3] *= a4.w;
        }
      }

      float psum = 0.f;
      uint2 pk[4];
#pragma unroll
      for (int mt = 0; mt < 4; ++mt) {
        const float p0 = fexp2(St[mt][0] - m_i);
        const float p1 = fexp2(St[mt][1] - m_i);
        const float p2 = fexp2(St[mt][2] - m_i);
        const float p3 = fexp2(St[mt][3] - m_i);
        psum += (p0 + p1) + (p2 + p3);
        pk[mt].x = pack_bf16_rn(p0, p1);
        pk[mt].y = pack_bf16_rn(p2, p3);
      }
      psum += __shfl_xor(psum, 16, 64);
      psum += __shfl_xor(psum, 32, 64);
      l_i = l_i * alpha + psum;

      // PV in two k-halves, reusing the 16x40 wave-private Pb region.
      // half A: kpos 0..31
#pragma unroll
      for (int mt = 0; mt < 2; ++mt)
        *reinterpret_cast<uint2*>(&Pb[w][r * 40 + 16 * mt + 4 * quad]) = pk[mt];
      {
        const short8 pa0 = *reinterpret_cast<const short8*>(&Pb[w][r * 40 + 8 * quad]);
        __builtin_amdgcn_s_setprio(1);
#pragma unroll
        for (int dt = 0; dt < 8; ++dt) {
          const int d = 16 * dt + r;
          const short8 b0 = *reinterpret_cast<const short8*>(&Vs[d * 64 + 8 * (quad ^ sw)]);
          Oc[dt] = __builtin_amdgcn_mfma_f32_16x16x32_bf16(pa0, b0, Oc[dt], 0, 0, 0);
        }
        __builtin_amdgcn_s_setprio(0);
      }
      // half B: kpos 32..63 (same-wave LDS in-order: safe overwrite)
#pragma unroll
      for (int mt = 2; mt < 4; ++mt)
        *reinterpret_cast<uint2*>(&Pb[w][r * 40 + 16 * (mt - 2) + 4 * quad]) = pk[mt];
      {
        const short8 pa1 = *reinterpret_cast<const short8*>(&Pb[w][r * 40 + 8 * quad]);
        __builtin_amdgcn_s_setprio(1);
#pragma unroll
        for (int dt = 0; dt < 8; ++dt) {
          const int d = 16 * dt + r;
          const short8 b1 = *reinterpret_cast<const short8*>(&Vs[d * 64 + 8 * ((4 + quad) ^ sw)]);
          Oc[dt] = __builtin_amdgcn_mfma_f32_16x16x32_bf16(pa1, b1, Oc[dt], 0, 0, 0);
        }
        __builtin_amdgcn_s_setprio(0);
      }
    }

    // normalize by 1/l (LDS broadcast, wave-private)
    if (quad == 0) ab[w][r] = 1.0f / l_i;
    const float4 li4 = *reinterpret_cast<const float4*>(&ab[w][4 * quad]);
#pragma unroll
    for (int dt = 0; dt < 8; ++dt) {
      Oc[dt][0] *= li4.x; Oc[dt][1] *= li4.y; Oc[dt][2] *= li4.z; Oc[dt][3] *= li4.w;
    }
  };

  f32x4 Ocr[8];  // cross-attn result, normalized, held in regs
  run_pass(Qc, Kc, Vc, kvLenC, Ocr);
  __syncthreads();  // all cross LDS reads done before main re-stages
  f32x4 Oc[8];
  run_pass(Qm, Km, Vm, kvLenM, Oc);

  // store bf16: main + cross (register add)
  u16* obb = Ob + (size_t)(q0 + 16 * w) * 1536 + h * 128;
#pragma unroll
  for (int rr = 0; rr < 4; ++rr) {
    u16* brow = obb + (size_t)(4 * quad + rr) * 1536 + r;
#pragma unroll
    for (int dt = 0; dt < 8; ++dt)
      brow[16 * dt] = f2b(Oc[dt][rr] + Ocr[dt][rr]);
  }
}

// =====================================================================
// Host orchestration (5 dispatches)
// =====================================================================
extern "C" void kernel_launch(void* const* d_in, const int* in_sizes, int n_in,
                              void* d_out, int out_size, void* d_ws, size_t ws_size,
                              hipStream_t stream) {
  (void)in_sizes; (void)n_in; (void)out_size; (void)ws_size;
  constexpr int T = 4096, TR = 1024, DIM = 1536, NH = 12;

  const float* hs  = (const float*)d_in[0];
  const float* rhs = (const float*)d_in[1];
  const float* rc  = (const float*)d_in[2];
  const float* rs  = (const float*)d_in[3];
  const float* Wq  = (const float*)d_in[4];
  const float* bq  = (const float*)d_in[5];
  const float* Wk  = (const float*)d_in[6];
  const float* bk  = (const float*)d_in[7];
  const float* Wv  = (const float*)d_in[8];
  const float* bv  = (const float*)d_in[9];
  const float* Wkr = (const float*)d_in[10];
  const float* bkr = (const float*)d_in[11];
  const float* Wvr = (const float*)d_in[12];
  const float* bvr = (const float*)d_in[13];
  const float* Wo  = (const float*)d_in[14];
  const float* bo  = (const float*)d_in[15];
  const float* gq  = (const float*)d_in[16];
  const float* gk  = (const float*)d_in[17];
  float* out = (float*)d_out;

  char* ws = (char*)d_ws;
  size_t off = 0;
  auto alloc = [&](size_t bytes) -> void* {
    void* p = ws + off;
    off += (bytes + 255) & ~(size_t)255;
    return p;
  };
  u16* bQ    = (u16*)alloc((size_t)T * DIM * 2);
  u16* bQr   = (u16*)alloc((size_t)T * DIM * 2);
  u16* bK    = (u16*)alloc((size_t)T * DIM * 2);
  u16* bV    = (u16*)alloc((size_t)T * DIM * 2);
  u16* bKr   = (u16*)alloc((size_t)TR * DIM * 2);
  u16* bVr   = (u16*)alloc((size_t)TR * DIM * 2);
  u16* bHs   = (u16*)alloc((size_t)T * DIM * 2);       // bf16 hs; ALIAS-> VtG
  u16* bRhs  = (u16*)alloc((size_t)TR * DIM * 2);      // bf16 rhs; ALIAS-> VtR
  u16* bWqkv = (u16*)alloc((size_t)3 * DIM * DIM * 2); // WqT|WkT|WvT; ALIAS-> bOb
  u16* bWr   = (u16*)alloc((size_t)2 * DIM * DIM * 2); // WkrT|WvrT
  u16* bWoT  = (u16*)alloc((size_t)DIM * DIM * 2);     // WoT (own slab)
  u16* VtG = bHs;
  u16* VtR = bRhs;
  u16* bOb = bWqkv;

  const dim3 blk(256);

  // 1. fused prep: f32->bf16 converts (z=0) + 6 weight transposes (z=1)
  prep_kernel<<<dim3(3840, 1, 2), blk, 0, stream>>>(
      hs, bHs, T * DIM / 8, rhs, bRhs, TR * DIM / 8,
      Wq, Wk, Wv, Wkr, Wvr, Wo,
      bWqkv + 0 * (size_t)DIM * DIM, bWqkv + 1 * (size_t)DIM * DIM,
      bWqkv + 2 * (size_t)DIM * DIM, bWr + 0 * (size_t)DIM * DIM,
      bWr + 1 * (size_t)DIM * DIM, bWoT);

  // 2. merged projections: QKV (1152 blocks) + KrVr (192 blocks)
  gemm_qkvr_kernel<<<dim3(1344), blk, 0, stream>>>(
      bHs, bWqkv, bQ, bK, bV, bq, bk, bv,
      bRhs, bWr, bKr, bVr, bkr, bvr);

  // 3. fused rmsnorm/rope + per-head V transposes
  normtrans_kernel<<<dim3(12288 + 1536), blk, 0, stream>>>(
      bQ, bK, bKr, gq, gk, rc, rs, bQ, bQr, bK, bKr,
      bV, VtG, bVr, VtR);

  // 4. merged flash attention: cross (kv=1024) + main (kv=4096), adds in regs
  flash_kernel<<<dim3(T / 64, NH), blk, 0, stream>>>(
      bQ, bKr, VtR, TR, bQr, bK, VtG, T, bOb);

  // 5. output projection (64-row tiles for occupancy)
  gemm128_kernel<2, float><<<dim3(12, 64), blk, 0, stream>>>(
      bOb, DIM, bWoT, DIM, out, (float*)nullptr, (float*)nullptr, DIM, bo, nullptr, nullptr, DIM);
}